// Round 7
// baseline (148.175 us; speedup 1.0000x reference)
//
#include <hip/hip_runtime.h>
#include <cstdint>

#define PI_F 3.14159265358979323846f

__device__ __forceinline__ float fract_(float x)  { return __builtin_amdgcn_fractf(x); }
__device__ __forceinline__ float sin2pi_(float r) { return __builtin_amdgcn_sinf(r); }  // sin(2*pi*r)
__device__ __forceinline__ float cos2pi_(float r) { return __builtin_amdgcn_cosf(r); }  // cos(2*pi*r)

// ---------------------------------------------------------------------------
// Single fused kernel, trajectory bit-identical to round-1 (absmax 36.0).
//
// Block = 576 threads = 9 waves, 64 items (item = lane).
//  * waves 0..7: chain waves. Round-5-PROVEN bit-exact decomposition: wave
//    wv = 2*w_ + h owns chains m = {2h, 2h+1} of round-1 wave group w_;
//    partial = acc0+acc1; fold (r0+r1)+(r2+r3) etc. reproduces round-1's S.
//    They never touch the head -> 576 instr/wave-iter.
//  * wave 8: head wave. Owns u0,u1; runs the VERBATIM round-1 head + update
//    once per block (not once per wave like r4/r5) and broadcasts
//    {crev, C4, S4} (exact bits) via double-buffered LDS.
//  * pack fused in: threads 0..511 each build one 32-bit sign word per array
//    from 8 independent float4 loads (round-4-proven bit layout), straight
//    into LDS. No ballot, no second dispatch, no global packed array.
//
// Schedule per iter: chains(read bc[p]) -> red[p] -> BARRIER1 ->
// wave8: fold, update, head(t+1) -> bc[p^1] -> BARRIER2. Buffer parity makes
// every RAW/WAR hazard span a barrier (audited per-buffer).
// ---------------------------------------------------------------------------
extern "C" __global__ void __launch_bounds__(576, 2)
refine_fused(const float4* __restrict__ zr4, const float4* __restrict__ zi4,
             const float* __restrict__ th0, const float* __restrict__ r0,
             const float* __restrict__ a_th_raw, const float* __restrict__ a_r_raw,
             const float* __restrict__ l_th_raw, const float* __restrict__ l_r_raw,
             float* __restrict__ out) {
    const int tid   = threadIdx.x;
    const int lane  = tid & 63;
    const int wv    = tid >> 6;              // wave 0..8
    const int item0 = blockIdx.x * 64;

    __shared__ uint32_t s_pr[64][8];         // [item][k-word] sign bits, z_real
    __shared__ uint32_t s_pi[64][8];         // [item][k-word] sign bits, z_imag
    __shared__ float    sp[4][10];           // ath, ar, lth, lr per step
    __shared__ float    bc[2][3][64];        // {crev, C4, S4} broadcast, parity-buffered
    __shared__ float    red[2][8][64];       // chain partials, parity-buffered

    float u0 = 0.0f, u1 = 0.0f, T0 = 0.0f, T1 = 0.0f, cth = 0.0f;

    if (wv < 8) {
        // ---- pack: thread tid builds word (tid&7) of item (tid>>3) ----
        // element (32*wd + 4q + j) -> bit (4q+j): identical layout to the
        // round-4 pack_signs kernel (proven bit-compatible, absmax 36.0).
        const int it = tid >> 3, wd = tid & 7;
        const size_t f4 = (size_t)(item0 + it) * 64 + (size_t)wd * 8;
        uint32_t wr = 0u, wi = 0u;
        #pragma unroll
        for (int q = 0; q < 8; ++q) {
            const float4 a = zr4[f4 + q];
            const float4 b = zi4[f4 + q];
            wr |= ((uint32_t)(a.x < 0.f) << (4 * q))     | ((uint32_t)(a.y < 0.f) << (4 * q + 1))
                | ((uint32_t)(a.z < 0.f) << (4 * q + 2)) | ((uint32_t)(a.w < 0.f) << (4 * q + 3));
            wi |= ((uint32_t)(b.x < 0.f) << (4 * q))     | ((uint32_t)(b.y < 0.f) << (4 * q + 1))
                | ((uint32_t)(b.z < 0.f) << (4 * q + 2)) | ((uint32_t)(b.w < 0.f) << (4 * q + 3));
        }
        s_pr[it][wd] = wr;
        s_pi[it][wd] = wi;
    } else {
        // ---- head wave prologue ----
        if (lane < 40) {
            const int a = lane / 10, i = lane % 10;
            const float* src = (a == 0) ? a_th_raw : (a == 1) ? a_r_raw
                             : (a == 2) ? l_th_raw : l_r_raw;
            const float v  = log1pf(expf(src[i]));       // verbatim round-1 expr
            const float hi = (a < 2) ? 0.2f : 1.0f;
            sp[a][i] = fminf(fmaxf(v, 1e-6f), hi);
        }
        // u0 = atanh(theta/60), u1 = atanh(2*(r/2000)-1) -- verbatim round-1
        const int item = item0 + lane;
        float y = th0[item] * (1.0f / 60.0f);
        y = fminf(fmaxf(y, -1.0f + 1e-6f), 1.0f - 1e-6f);
        u0 = atanhf(y);
        float sR = r0[item] * (1.0f / 2000.0f);
        sR = fminf(fmaxf(sR, 1e-6f), 1.0f - 1e-6f);
        u1 = atanhf(2.0f * sR - 1.0f);

        // head for t=0 (verbatim round-1 expressions)
        T0 = tanhf(u0);
        T1 = tanhf(u1);
        const float th_rad = (PI_F / 3.0f) * T0;
        const float sth = sinf(th_rad);
        cth = cosf(th_rad);
        const float r    = 1000.0f * (T1 + 1.0f);
        const float crev = 0.5f * sth - 2e-4f * r;
        const float d4   = fract_(4.0f * crev);
        bc[0][0][lane] = crev;
        bc[0][1][lane] = cos2pi_(d4);
        bc[0][2][lane] = sin2pi_(d4);
    }
    __syncthreads();                          // pack + sp + bc[0] ready

    // chain-wave constants (round-5-proven decomposition)
    const int w_ = wv >> 1;                   // round-1 wave group 0..3
    const int mA = 2 * (wv & 1);              // this wave's chains: mA, mA+1
    uint32_t br0 = 0, br1 = 0, bi0 = 0, bi1 = 0;
    if (wv < 8) {
        br0 = s_pr[lane][2 * w_ + 0];
        br1 = s_pr[lane][2 * w_ + 1];
        bi0 = s_pi[lane][2 * w_ + 0];
        bi1 = s_pi[lane][2 * w_ + 1];
    }
    const float w64 = (float)(w_ * 64);

    for (int t = 0; t < 10; ++t) {
        const int p = t & 1;

        if (wv < 8) {
            const float crev = bc[p][0][lane];
            const float C4   = bc[p][1][lane];
            const float S4   = bc[p][2][lane];

            // ---- two chains, verbatim round-1/round-5 inner arithmetic ----
            float c[2], s[2], kf[2], acc[2];
            #pragma unroll
            for (int mm = 0; mm < 2; ++mm) {
                const float k0 = w64 + (float)(mA + mm);
                const float rv = fract_(k0 * crev);
                c[mm]   = cos2pi_(rv);
                s[mm]   = sin2pi_(rv);
                kf[mm]  = k0;
                acc[mm] = 0.0f;
            }

            #pragma unroll
            for (int j = 0; j < 16; ++j) {
                #pragma unroll
                for (int mm = 0; mm < 2; ++mm) {
                    const int kl = (mA + mm) + 4 * j;      // 0..63, compile-time
                    const uint32_t wr = (kl < 32) ? br0 : br1;
                    const uint32_t wi = (kl < 32) ? bi0 : bi1;
                    const int sh = 31 - (kl & 31);
                    const uint32_t mre = (wr << sh) & 0x80000000u;
                    const uint32_t mim = (wi << sh) & 0x80000000u;
                    const float cs = c[mm], ss = s[mm];
                    const float zc = __uint_as_float(__float_as_uint(cs) ^ mim); // z_im*cos
                    const float zs = __uint_as_float(__float_as_uint(ss) ^ mre); // z_re*sin
                    const float w0 = zc - zs;
                    // cubic sigma term: -sin(4phi)/786432 = -s*c*(1-2s^2)/196608
                    const float u2 = ss * ss;
                    const float t2 = fmaf(-2.0f, u2, 1.0f);
                    const float sc = ss * cs;
                    const float v  = sc * t2;
                    const float Wk = fmaf(v, -(1.0f / 196608.0f), w0 * 0.0625f);
                    acc[mm] = fmaf(kf[mm], Wk, acc[mm]);
                    kf[mm] += 4.0f;
                    const float tA = ss * S4;
                    const float tB = cs * S4;
                    c[mm] = fmaf(cs, C4, -tA);
                    s[mm] = fmaf(ss, C4, tB);
                }
            }
            red[p][wv][lane] = acc[0] + acc[1];   // round-1's (a_{2h}+a_{2h+1})
        }
        __syncthreads();                          // barrier 1: partials ready

        if (wv == 8) {
            // round-1 exact fold tree
            const float S0 = red[p][0][lane] + red[p][1][lane];   // group 0
            const float S1 = red[p][2][lane] + red[p][3][lane];   // group 1
            const float S2 = red[p][4][lane] + red[p][5][lane];   // group 2
            const float S3 = red[p][6][lane] + red[p][7][lane];   // group 3
            const float S  = (S0 + S1) + (S2 + S3);

            const float ath = sp[0][t], ar = sp[1][t], lth = sp[2][t], lr = sp[3][t];

            // ---- update, verbatim round-1 (T0,T1,cth held from this iter's head) ----
            const float g0 = -(PI_F * PI_F / 3.0f) * cth * (1.0f - T0 * T0) * S;
            const float g1 = 0.4f * PI_F * (1.0f - T1 * T1) * S;
            const float den0 = fmaxf(fabsf(g0), 1e-6f) + lth;
            const float den1 = fmaxf(fabsf(g1), 1e-6f) + lr;
            float st0 = ath * g0 / den0;
            float st1 = ar  * g1 / den1;
            st0 = fminf(fmaxf(st0, -0.1f), 0.1f);
            st1 = fminf(fmaxf(st1, -0.1f), 0.1f);
            u0 -= st0;
            u1 -= st1;

            // ---- head for t+1, verbatim round-1 expressions ----
            if (t < 9) {
                T0 = tanhf(u0);
                T1 = tanhf(u1);
                const float th_rad = (PI_F / 3.0f) * T0;
                const float sth = sinf(th_rad);
                cth = cosf(th_rad);
                const float r     = 1000.0f * (T1 + 1.0f);
                const float crevN = 0.5f * sth - 2e-4f * r;
                const float d4    = fract_(4.0f * crevN);
                bc[p ^ 1][0][lane] = crevN;
                bc[p ^ 1][1][lane] = cos2pi_(d4);
                bc[p ^ 1][2][lane] = sin2pi_(d4);
            }
        }
        __syncthreads();                          // barrier 2: bc[p^1] ready
    }

    if (wv == 8) {
        const float thT = 60.0f * tanhf(u0);
        const float rT  = 1000.0f * (tanhf(u1) + 1.0f);
        reinterpret_cast<float2*>(out)[item0 + lane] = make_float2(thT, rT);
    }
}

extern "C" void kernel_launch(void* const* d_in, const int* in_sizes, int n_in,
                              void* d_out, int out_size, void* d_ws, size_t ws_size,
                              hipStream_t stream) {
    const float* zr   = (const float*)d_in[0];
    const float* zi   = (const float*)d_in[1];
    const float* th0  = (const float*)d_in[2];
    const float* r0   = (const float*)d_in[3];
    const float* athr = (const float*)d_in[4];
    const float* arr  = (const float*)d_in[5];
    const float* lthr = (const float*)d_in[6];
    const float* lrr  = (const float*)d_in[7];

    const int B = in_sizes[2];               // 32768 items

    refine_fused<<<B / 64, 576, 0, stream>>>((const float4*)zr, (const float4*)zi,
                                             th0, r0, athr, arr, lthr, lrr,
                                             (float*)d_out);
}